// Round 5
// baseline (60.500 us; speedup 1.0000x reference)
//
#include <hip/hip_runtime.h>

#define BATCH      131072
#define NBLK_MAIN  1024    // 256 threads/block, 2 threads/sample -> 128 samples/block
#define NBLK_BN    512

// ---------------------------------------------------------------------------
// Kernel 1: TWO threads per sample, wave-coalesced loading.
//   Each wave owns 32 samples: 8 chunks of 4 samples:
//     - 9 x (64 lanes x 16 B = 1 KB) contiguous global loads to regs
//     - ds_write into padded per-sample LDS layout (580-float stride)
//     - all 64 lanes pool one 6x6 block each -> 1 pooled value/lane/chunk
//   Redistribute via LDS (overlaid on stage, barrier-separated) so the lane
//   pair (2l,2l+1) owns sample l: even lane pooled[0..7], odd pooled[8..15].
//   One shfl_xor completes the encoding dot; circuit+MLP run redundantly in
//   the pair; even lane stores {o0,o1}, odd {o2,o3} (contiguous 8 B/lane).
// ---------------------------------------------------------------------------
__global__ __launch_bounds__(256, 4) void qnat_main(
    const float* __restrict__ x,
    const float* __restrict__ Wenc, const float* __restrict__ benc,
    const float* __restrict__ W1,   const float* __restrict__ b1,
    const float* __restrict__ W2,   const float* __restrict__ b2,
    float* __restrict__ out_pre, float* __restrict__ partials)
{
    // Weights: Wenc[64] | benc[4] | W1[128] | b1[32] | W2[128] | b2[4]
    __shared__ float sW[360];
    __shared__ __align__(16) float stage[4][2320];  // per-wave: 4 samples x 580
    __shared__ float redS[4][8];

    const int t = threadIdx.x;
    if (t < 64)  sW[t]       = Wenc[t];
    if (t < 4)   sW[64 + t]  = benc[t];
    if (t < 128) sW[68 + t]  = W1[t];
    if (t < 32)  sW[196 + t] = b1[t];
    if (t < 128) sW[228 + t] = W2[t];
    if (t < 4)   sW[356 + t] = b2[t];
    __syncthreads();

    const int wave = t >> 6, lane = t & 63;
    const int waveSampleBase = blockIdx.x * 128 + wave * 32;  // 32 samples/wave
    float* st = stage[wave];

    // pooling geometry: chunk = 4 samples x 16 pooled cells = 64 lanes
    const int s_loc = lane >> 4;          // sample-within-chunk 0..3
    const int slot  = lane & 15;          // pooled cell index
    const int spr   = slot >> 2, spc = slot & 3;
    const int rdOff = s_loc * 580 + spr * 144 + spc * 6;

    const float4* xg = reinterpret_cast<const float4*>(x);
    const unsigned gbase = (unsigned)waveSampleBase * 144u;   // float4 index

    float pv[8];
    #pragma unroll
    for (int c = 0; c < 8; ++c) {
        // ---- 9 wave-contiguous 1-KB loads (chunk = 4 samples = 576 float4) ----
        float4 v[9];
        #pragma unroll
        for (int i = 0; i < 9; ++i)
            v[i] = xg[gbase + (unsigned)c * 576u + (unsigned)i * 64u + (unsigned)lane];
        // ---- scatter to padded LDS layout ----
        #pragma unroll
        for (int i = 0; i < 9; ++i) {
            const int g = i * 64 + lane;        // 0..575 float4 within chunk
            const int s = g / 144;              // sample 0..3
            const int q = g - s * 144;          // float4 within sample
            *reinterpret_cast<float4*>(&st[s * 580 + q * 4]) = v[i];
        }
        // ---- pool this lane's 6x6 block ----
        float acc = 0.f;
        #pragma unroll
        for (int r = 0; r < 6; ++r) {
            const float2 a  = *reinterpret_cast<const float2*>(&st[rdOff + r * 24 + 0]);
            const float2 bb = *reinterpret_cast<const float2*>(&st[rdOff + r * 24 + 2]);
            const float2 cc = *reinterpret_cast<const float2*>(&st[rdOff + r * 24 + 4]);
            acc += a.x + a.y + bb.x + bb.y + cc.x + cc.y;
        }
        pv[c] = acc * (1.f / 36.f);
    }

    // ---- redistribute via LDS overlay: pb[sample*17 + slot] ----
    __syncthreads();                       // stage reads done everywhere
    float* pb = st;                        // 32*17 = 544 floats <= 2320
    #pragma unroll
    for (int c = 0; c < 8; ++c)
        pb[(c * 4 + s_loc) * 17 + slot] = pv[c];
    __syncthreads();                       // pb writes visible

    const int myS = lane >> 1;             // sample-within-wave 0..31
    const int k0  = (lane & 1) * 8;        // this lane's pooled half
    float p8[8];
    #pragma unroll
    for (int q = 0; q < 8; ++q)
        p8[q] = pb[myS * 17 + k0 + q];

    // ---- encoding: half-dot + pair shfl; angles -> cos/sin of half ----
    float ch[4], sh[4];
    #pragma unroll
    for (int j = 0; j < 4; ++j) {
        float e = 0.f;
        #pragma unroll
        for (int q = 0; q < 8; ++q) e = fmaf(p8[q], sW[j * 16 + k0 + q], e);
        e += __shfl_xor(e, 1);
        const float h = 0.5f * (e + sW[64 + j]);
        ch[j] = cosf(h);
        sh[j] = sinf(h);
    }

    // ---- 4-qubit statevector (redundant in the lane pair) ----
    float re[16], im[16];
    #pragma unroll
    for (int i = 0; i < 16; ++i) { re[i] = 0.f; im[i] = 0.f; }
    re[0] = 1.f;

    // RY(w): [[c,-s],[s,c]]
    #pragma unroll
    for (int w = 0; w < 4; ++w) {
        const int bit = 8 >> w;
        #pragma unroll
        for (int i = 0; i < 16; ++i) if (!(i & bit)) {
            const int jj = i | bit;
            const float r0 = re[i], m0 = im[i], r1 = re[jj], m1 = im[jj];
            re[i]  = ch[w] * r0 - sh[w] * r1;  im[i]  = ch[w] * m0 - sh[w] * m1;
            re[jj] = sh[w] * r0 + ch[w] * r1;  im[jj] = sh[w] * m0 + ch[w] * m1;
        }
    }
    // RZ(w): diag(e^{-ih}, e^{+ih})
    #pragma unroll
    for (int w = 0; w < 4; ++w) {
        const int bit = 8 >> w;
        #pragma unroll
        for (int i = 0; i < 16; ++i) {
            const float sg = (i & bit) ? 1.f : -1.f;
            const float r = re[i], m = im[i];
            re[i] = ch[w] * r - sg * sh[w] * m;
            im[i] = ch[w] * m + sg * sh[w] * r;
        }
    }
    // CNOTs on adjacent wires: pure register swaps
    #define SWAP_AMP(a, b) { float tr = re[a]; re[a] = re[b]; re[b] = tr; \
                             float ti = im[a]; im[a] = im[b]; im[b] = ti; }
    SWAP_AMP(8, 12)  SWAP_AMP(9, 13)  SWAP_AMP(10, 14) SWAP_AMP(11, 15)
    SWAP_AMP(4, 6)   SWAP_AMP(5, 7)   SWAP_AMP(12, 14) SWAP_AMP(13, 15)
    SWAP_AMP(2, 3)   SWAP_AMP(6, 7)   SWAP_AMP(10, 11) SWAP_AMP(14, 15)
    #undef SWAP_AMP

    // RX(w): [[c,-is],[-is,c]]
    #pragma unroll
    for (int w = 0; w < 4; ++w) {
        const int bit = 8 >> w;
        #pragma unroll
        for (int i = 0; i < 16; ++i) if (!(i & bit)) {
            const int jj = i | bit;
            const float r0 = re[i], m0 = im[i], r1 = re[jj], m1 = im[jj];
            re[i]  = ch[w] * r0 + sh[w] * m1;  im[i]  = ch[w] * m0 - sh[w] * r1;
            re[jj] = sh[w] * m0 + ch[w] * r1;  im[jj] = ch[w] * m1 - sh[w] * r0;
        }
    }

    // ---- PauliZ expectations ----
    float ez[4];
    #pragma unroll
    for (int w = 0; w < 4; ++w) {
        const int bit = 8 >> w;
        float acc = 0.f;
        #pragma unroll
        for (int i = 0; i < 16; ++i) {
            const float p = re[i] * re[i] + im[i] * im[i];
            acc += (i & bit) ? -p : p;
        }
        ez[w] = acc;
    }

    // ---- MLP: h = relu(ez @ W1^T + b1); out = h @ W2^T + b2 ----
    float o0 = sW[356], o1 = sW[357], o2 = sW[358], o3 = sW[359];
    #pragma unroll
    for (int i = 0; i < 32; ++i) {
        float h = sW[196 + i];
        #pragma unroll
        for (int j = 0; j < 4; ++j) h = fmaf(ez[j], sW[68 + i * 4 + j], h);
        h = fmaxf(h, 0.f);
        o0 = fmaf(h, sW[228 +  0 + i], o0);
        o1 = fmaf(h, sW[228 + 32 + i], o1);
        o2 = fmaf(h, sW[228 + 64 + i], o2);
        o3 = fmaf(h, sW[228 + 96 + i], o3);
    }

    // ---- store: pair-split float2, perfectly contiguous across the wave ----
    const int sGlob = waveSampleBase + myS;
    const float2 ov = (lane & 1) ? make_float2(o2, o3) : make_float2(o0, o1);
    reinterpret_cast<float2*>(out_pre)[sGlob * 2 + (lane & 1)] = ov;

    // ---- BN partials (even lanes only contribute; odd are duplicates) ----
    {
        const float m = (lane & 1) ? 0.f : 1.f;
        float v8[8] = { m * o0, m * o1, m * o2, m * o3,
                        m * o0 * o0, m * o1 * o1, m * o2 * o2, m * o3 * o3 };
        #pragma unroll
        for (int off = 32; off; off >>= 1) {
            #pragma unroll
            for (int k = 0; k < 8; ++k) v8[k] += __shfl_down(v8[k], off);
        }
        if (lane == 0) {
            #pragma unroll
            for (int k = 0; k < 8; ++k) redS[wave][k] = v8[k];
        }
        __syncthreads();
        if (t < 8) {
            partials[blockIdx.x * 8 + t] =
                redS[0][t] + redS[1][t] + redS[2][t] + redS[3][t];
        }
    }
}

// ---------------------------------------------------------------------------
// Kernel 2: reduce 1024 block-partials -> scale/shift (8 floats in d_ws).
// ---------------------------------------------------------------------------
__global__ __launch_bounds__(512) void qnat_reduce(
    const float* __restrict__ partials, const float* __restrict__ gamma,
    const float* __restrict__ beta, float* __restrict__ ss)
{
    const int t = threadIdx.x;   // 0..511, two partial rows each
    const float4* p4 = reinterpret_cast<const float4*>(partials);
    const float4 a0 = p4[t * 4 + 0], a1 = p4[t * 4 + 1];   // row 2t
    const float4 a2 = p4[t * 4 + 2], a3 = p4[t * 4 + 3];   // row 2t+1
    float v[8] = { a0.x + a2.x, a0.y + a2.y, a0.z + a2.z, a0.w + a2.w,
                   a1.x + a3.x, a1.y + a3.y, a1.z + a3.z, a1.w + a3.w };
    #pragma unroll
    for (int off = 32; off; off >>= 1) {
        #pragma unroll
        for (int k = 0; k < 8; ++k) v[k] += __shfl_down(v[k], off);
    }
    __shared__ float red[8][8];
    const int wave = t >> 6, lane = t & 63;
    if (lane == 0) {
        #pragma unroll
        for (int k = 0; k < 8; ++k) red[wave][k] = v[k];
    }
    __syncthreads();
    if (t < 4) {
        float sum = 0.f, sumsq = 0.f;
        #pragma unroll
        for (int w = 0; w < 8; ++w) { sum += red[w][t]; sumsq += red[w][4 + t]; }
        const float invB  = 1.f / (float)BATCH;
        const float mean  = sum * invB;
        const float var   = sumsq * invB - mean * mean;
        const float scale = gamma[t] / sqrtf(var + 1e-5f);
        ss[t]     = scale;
        ss[4 + t] = beta[t] - mean * scale;
    }
}

// ---------------------------------------------------------------------------
// Kernel 3: apply BN in place on d_out: out = pre * scale[j] + shift[j].
// ---------------------------------------------------------------------------
__global__ __launch_bounds__(256) void qnat_bn(
    float* __restrict__ io, const float* __restrict__ ss)
{
    __shared__ float s8[8];
    if (threadIdx.x < 8) s8[threadIdx.x] = ss[threadIdx.x];
    __syncthreads();
    const int idx = blockIdx.x * 256 + threadIdx.x;   // one sample (float4) each
    float4* p = reinterpret_cast<float4*>(io);
    float4 v = p[idx];
    v.x = fmaf(v.x, s8[0], s8[4]);
    v.y = fmaf(v.y, s8[1], s8[5]);
    v.z = fmaf(v.z, s8[2], s8[6]);
    v.w = fmaf(v.w, s8[3], s8[7]);
    p[idx] = v;
}

extern "C" void kernel_launch(void* const* d_in, const int* in_sizes, int n_in,
                              void* d_out, int out_size, void* d_ws, size_t ws_size,
                              hipStream_t stream)
{
    const float* x     = (const float*)d_in[0];
    const float* Wenc  = (const float*)d_in[1];
    const float* benc  = (const float*)d_in[2];
    const float* W1    = (const float*)d_in[3];
    const float* b1    = (const float*)d_in[4];
    const float* W2    = (const float*)d_in[5];
    const float* b2    = (const float*)d_in[6];
    const float* gamma = (const float*)d_in[7];
    const float* beta  = (const float*)d_in[8];

    float* out      = (float*)d_out;
    float* partials = (float*)d_ws;                 // 1024 * 8 floats = 32 KB
    float* ss       = partials + NBLK_MAIN * 8;     // 8 floats (scale, shift)

    qnat_main<<<NBLK_MAIN, 256, 0, stream>>>(x, Wenc, benc, W1, b1, W2, b2,
                                             out, partials);
    qnat_reduce<<<1, 512, 0, stream>>>(partials, gamma, beta, ss);
    qnat_bn<<<NBLK_BN, 256, 0, stream>>>(out, ss);
}

// Round 7
// 58.192 us; speedup vs baseline: 1.0397x; 1.0397x over previous
//
#include <hip/hip_runtime.h>

#define BATCH      131072
#define NBLK_MAIN  512     // 256 threads/block, 1 sample/thread
#define NBLK_BN    512

// ---------------------------------------------------------------------------
// Kernel 1 (identical to validated R4): one thread per sample, wave-coalesced
// loading. Each wave owns 64 samples; 16 chunks of 4 samples:
//   - 9 x (64 lanes x 16 B = 1 KB) contiguous global loads to regs
//   - ds_write into padded per-sample LDS layout (580-float stride)
//   - 16 lanes/sample pool one 6x6 block each -> 1 pooled value/lane/chunk
// Redistribute pooled values via LDS; circuit + MLP + BN partials.
// ---------------------------------------------------------------------------
__global__ __launch_bounds__(256, 2) void qnat_main(
    const float* __restrict__ x,
    const float* __restrict__ Wenc, const float* __restrict__ benc,
    const float* __restrict__ W1,   const float* __restrict__ b1,
    const float* __restrict__ W2,   const float* __restrict__ b2,
    float* __restrict__ out_pre, float* __restrict__ partials)
{
    // Weights: Wenc[64] | benc[4] | W1[128] | b1[32] | W2[128] | b2[4]
    __shared__ float sW[360];
    __shared__ __align__(16) float stage[4][2320];  // per-wave: 4 samples x 580 (576+4 pad)
    __shared__ float pbuf[4][1088];                 // per-wave: 64 samples x 17 (16+1 pad)
    __shared__ float redS[4][8];

    const int t = threadIdx.x;
    if (t < 64)  sW[t]       = Wenc[t];
    if (t < 4)   sW[64 + t]  = benc[t];
    if (t < 128) sW[68 + t]  = W1[t];
    if (t < 32)  sW[196 + t] = b1[t];
    if (t < 128) sW[228 + t] = W2[t];
    if (t < 4)   sW[356 + t] = b2[t];
    __syncthreads();

    const int wave = t >> 6, lane = t & 63;
    const int sampleBase = blockIdx.x * 256 + wave * 64;   // this wave's 64 samples
    float* st = stage[wave];
    float* pb = pbuf[wave];

    // pooling geometry: 16 lanes per sample; slot = pr*4+pc (6x6 block)
    const int s_loc = lane >> 4;          // sample-within-chunk 0..3
    const int slot  = lane & 15;          // pooled cell index
    const int spr   = slot >> 2, spc = slot & 3;
    const int rdOff = s_loc * 580 + spr * 144 + spc * 6;

    const float4* xg = reinterpret_cast<const float4*>(x);
    const unsigned gbase = (unsigned)sampleBase * 144u;    // float4 index of wave's region

    float pv[16];
    #pragma unroll
    for (int c = 0; c < 16; ++c) {
        // ---- 9 wave-contiguous 1-KB loads (chunk = 4 samples = 576 float4) ----
        float4 v[9];
        #pragma unroll
        for (int i = 0; i < 9; ++i)
            v[i] = xg[gbase + (unsigned)c * 576u + (unsigned)i * 64u + (unsigned)lane];
        // ---- scatter to padded LDS layout ----
        #pragma unroll
        for (int i = 0; i < 9; ++i) {
            const int g = i * 64 + lane;        // 0..575 float4 within chunk
            const int s = g / 144;              // sample 0..3
            const int q = g - s * 144;          // float4 within sample
            *reinterpret_cast<float4*>(&st[s * 580 + q * 4]) = v[i];
        }
        // ---- pool this lane's 6x6 block ----
        float acc = 0.f;
        #pragma unroll
        for (int r = 0; r < 6; ++r) {
            const float2 a  = *reinterpret_cast<const float2*>(&st[rdOff + r * 24 + 0]);
            const float2 bb = *reinterpret_cast<const float2*>(&st[rdOff + r * 24 + 2]);
            const float2 cc = *reinterpret_cast<const float2*>(&st[rdOff + r * 24 + 4]);
            acc += a.x + a.y + bb.x + bb.y + cc.x + cc.y;
        }
        pv[c] = acc * (1.f / 36.f);
    }

    // ---- redistribute: lane l ends up owning sample l's 16 pooled values ----
    #pragma unroll
    for (int c = 0; c < 16; ++c)
        pb[(c * 4 + s_loc) * 17 + slot] = pv[c];
    float pooled[16];
    #pragma unroll
    for (int q = 0; q < 16; ++q)
        pooled[q] = pb[lane * 17 + q];

    // ---- encoding: enc = pooled @ Wenc^T + benc; angles -> cos/sin of half ----
    float ch[4], sh[4];
    #pragma unroll
    for (int j = 0; j < 4; ++j) {
        float e = sW[64 + j];
        #pragma unroll
        for (int k = 0; k < 16; ++k) e = fmaf(pooled[k], sW[j * 16 + k], e);
        const float h = 0.5f * e;
        ch[j] = cosf(h);
        sh[j] = sinf(h);
    }

    // ---- 4-qubit statevector, idx bit for wire w is 8>>w ----
    float re[16], im[16];
    #pragma unroll
    for (int i = 0; i < 16; ++i) { re[i] = 0.f; im[i] = 0.f; }
    re[0] = 1.f;

    // RY(w): [[c,-s],[s,c]]
    #pragma unroll
    for (int w = 0; w < 4; ++w) {
        const int bit = 8 >> w;
        #pragma unroll
        for (int i = 0; i < 16; ++i) if (!(i & bit)) {
            const int jj = i | bit;
            const float r0 = re[i], m0 = im[i], r1 = re[jj], m1 = im[jj];
            re[i]  = ch[w] * r0 - sh[w] * r1;  im[i]  = ch[w] * m0 - sh[w] * m1;
            re[jj] = sh[w] * r0 + ch[w] * r1;  im[jj] = sh[w] * m0 + ch[w] * m1;
        }
    }
    // RZ(w): diag(e^{-ih}, e^{+ih})
    #pragma unroll
    for (int w = 0; w < 4; ++w) {
        const int bit = 8 >> w;
        #pragma unroll
        for (int i = 0; i < 16; ++i) {
            const float sg = (i & bit) ? 1.f : -1.f;
            const float r = re[i], m = im[i];
            re[i] = ch[w] * r - sg * sh[w] * m;
            im[i] = ch[w] * m + sg * sh[w] * r;
        }
    }
    // CNOTs on adjacent wires: pure register swaps
    #define SWAP_AMP(a, b) { float tr = re[a]; re[a] = re[b]; re[b] = tr; \
                             float ti = im[a]; im[a] = im[b]; im[b] = ti; }
    SWAP_AMP(8, 12)  SWAP_AMP(9, 13)  SWAP_AMP(10, 14) SWAP_AMP(11, 15)
    SWAP_AMP(4, 6)   SWAP_AMP(5, 7)   SWAP_AMP(12, 14) SWAP_AMP(13, 15)
    SWAP_AMP(2, 3)   SWAP_AMP(6, 7)   SWAP_AMP(10, 11) SWAP_AMP(14, 15)
    #undef SWAP_AMP

    // RX(w): [[c,-is],[-is,c]]
    #pragma unroll
    for (int w = 0; w < 4; ++w) {
        const int bit = 8 >> w;
        #pragma unroll
        for (int i = 0; i < 16; ++i) if (!(i & bit)) {
            const int jj = i | bit;
            const float r0 = re[i], m0 = im[i], r1 = re[jj], m1 = im[jj];
            re[i]  = ch[w] * r0 + sh[w] * m1;  im[i]  = ch[w] * m0 - sh[w] * r1;
            re[jj] = sh[w] * m0 + ch[w] * r1;  im[jj] = ch[w] * m1 - sh[w] * r0;
        }
    }

    // ---- PauliZ expectations ----
    float ez[4];
    #pragma unroll
    for (int w = 0; w < 4; ++w) {
        const int bit = 8 >> w;
        float acc = 0.f;
        #pragma unroll
        for (int i = 0; i < 16; ++i) {
            const float p = re[i] * re[i] + im[i] * im[i];
            acc += (i & bit) ? -p : p;
        }
        ez[w] = acc;
    }

    // ---- MLP: h = relu(ez @ W1^T + b1); out = h @ W2^T + b2 ----
    float o0 = sW[356], o1 = sW[357], o2 = sW[358], o3 = sW[359];
    #pragma unroll
    for (int i = 0; i < 32; ++i) {
        float h = sW[196 + i];
        #pragma unroll
        for (int j = 0; j < 4; ++j) h = fmaf(ez[j], sW[68 + i * 4 + j], h);
        h = fmaxf(h, 0.f);
        o0 = fmaf(h, sW[228 +  0 + i], o0);
        o1 = fmaf(h, sW[228 + 32 + i], o1);
        o2 = fmaf(h, sW[228 + 64 + i], o2);
        o3 = fmaf(h, sW[228 + 96 + i], o3);
    }

    reinterpret_cast<float4*>(out_pre)[blockIdx.x * 256 + t] =
        make_float4(o0, o1, o2, o3);

    // ---- deterministic block reduction of sum / sumsq per feature ----
    {
        float v8[8] = { o0, o1, o2, o3, o0 * o0, o1 * o1, o2 * o2, o3 * o3 };
        #pragma unroll
        for (int off = 32; off; off >>= 1) {
            #pragma unroll
            for (int k = 0; k < 8; ++k) v8[k] += __shfl_down(v8[k], off);
        }
        if (lane == 0) {
            #pragma unroll
            for (int k = 0; k < 8; ++k) redS[wave][k] = v8[k];
        }
        __syncthreads();
        if (t < 8) {
            partials[blockIdx.x * 8 + t] =
                redS[0][t] + redS[1][t] + redS[2][t] + redS[3][t];
        }
    }
}

// ---------------------------------------------------------------------------
// Kernel 2: fused reduce + BN apply. Every block redundantly reduces the
// 512x8 partials (4 KB, L2-hot), computes scale/shift, then applies BN to
// its 256 samples of out (in place).
// ---------------------------------------------------------------------------
__global__ __launch_bounds__(256) void qnat_bn(
    const float* __restrict__ partials, const float* __restrict__ gamma,
    const float* __restrict__ beta, float* __restrict__ io)
{
    __shared__ float red[4][8];
    const int t = threadIdx.x;
    const int wave = t >> 6, lane = t & 63;

    // load this thread's sample early (overlaps the reduction)
    const int idx = blockIdx.x * 256 + t;
    float4* p = reinterpret_cast<float4*>(io);
    float4 v4 = p[idx];

    // thread t sums partial rows 2t and 2t+1 (row = 8 floats = 2 float4s)
    const float4* p4 = reinterpret_cast<const float4*>(partials);
    const float4 a0 = p4[t * 4 + 0], a1 = p4[t * 4 + 1];
    const float4 a2 = p4[t * 4 + 2], a3 = p4[t * 4 + 3];
    float v[8] = { a0.x + a2.x, a0.y + a2.y, a0.z + a2.z, a0.w + a2.w,
                   a1.x + a3.x, a1.y + a3.y, a1.z + a3.z, a1.w + a3.w };
    #pragma unroll
    for (int off = 32; off; off >>= 1) {
        #pragma unroll
        for (int k = 0; k < 8; ++k) v[k] += __shfl_down(v[k], off);
    }
    if (lane == 0) {
        #pragma unroll
        for (int k = 0; k < 8; ++k) red[wave][k] = v[k];
    }
    __syncthreads();

    float sc[4], sf[4];
    #pragma unroll
    for (int j = 0; j < 4; ++j) {
        const float sum   = red[0][j] + red[1][j] + red[2][j] + red[3][j];
        const float sumsq = red[0][4 + j] + red[1][4 + j] + red[2][4 + j] + red[3][4 + j];
        const float invB  = 1.f / (float)BATCH;
        const float mean  = sum * invB;
        const float var   = sumsq * invB - mean * mean;
        sc[j] = gamma[j] / sqrtf(var + 1e-5f);
        sf[j] = beta[j] - mean * sc[j];
    }

    v4.x = fmaf(v4.x, sc[0], sf[0]);
    v4.y = fmaf(v4.y, sc[1], sf[1]);
    v4.z = fmaf(v4.z, sc[2], sf[2]);
    v4.w = fmaf(v4.w, sc[3], sf[3]);
    p[idx] = v4;
}

extern "C" void kernel_launch(void* const* d_in, const int* in_sizes, int n_in,
                              void* d_out, int out_size, void* d_ws, size_t ws_size,
                              hipStream_t stream)
{
    const float* x     = (const float*)d_in[0];
    const float* Wenc  = (const float*)d_in[1];
    const float* benc  = (const float*)d_in[2];
    const float* W1    = (const float*)d_in[3];
    const float* b1    = (const float*)d_in[4];
    const float* W2    = (const float*)d_in[5];
    const float* b2    = (const float*)d_in[6];
    const float* gamma = (const float*)d_in[7];
    const float* beta  = (const float*)d_in[8];

    float* out      = (float*)d_out;
    float* partials = (float*)d_ws;    // 512 * 8 floats = 4 KB

    qnat_main<<<NBLK_MAIN, 256, 0, stream>>>(x, Wenc, benc, W1, b1, W2, b2,
                                             out, partials);
    qnat_bn<<<NBLK_BN, 256, 0, stream>>>(partials, gamma, beta, out);
}